// Round 8
// baseline (146.697 us; speedup 1.0000x reference)
//
#include <hip/hip_runtime.h>

namespace {

typedef unsigned short u16;
typedef __attribute__((ext_vector_type(8))) short short8;
typedef __attribute__((ext_vector_type(4))) float f32x4;
typedef __attribute__((ext_vector_type(4))) unsigned int u32x4;

constexpr int kD = 48;
constexpr int kSliceN = kD * kD * kD;  // 110592
constexpr int kP = 8;                  // partials per (c,t) slice

// DPP convention: row_shr:N -> out[n]=in[n-N]
constexpr int SHR1 = 0x111;   // out[n] = in[n-1]
constexpr int SHL1 = 0x101;   // out[n] = in[n+1]
constexpr int SHL15 = 0x10F;  // lane0 <- lane15
constexpr int SHR15 = 0x11F;  // lane15 <- lane0

__device__ inline u16 f2bf(float f) {
  unsigned u = __float_as_uint(f);
  u += 0x7fffu + ((u >> 16) & 1u);  // RNE
  return (u16)(u >> 16);
}

__device__ inline void gl_lds16(const void* g, void* l) {
  __builtin_amdgcn_global_load_lds(
      (const __attribute__((address_space(1))) unsigned int*)g,
      (__attribute__((address_space(3))) unsigned int*)l, 16, 0, 0);
}

template <int CM>
__device__ inline short8 dpp4(short8 m) {
  u32x4 mu = __builtin_bit_cast(u32x4, m), r;
  #pragma unroll
  for (int j = 0; j < 4; ++j)
    r[j] = (unsigned)__builtin_amdgcn_update_dpp(0, (int)mu[j], CM, 0xf, 0xf, true);
  return __builtin_bit_cast(short8, r);
}
template <int CM, int CP>
__device__ inline short8 dpp4p(short8 m, short8 nb, bool pl) {
  u32x4 mu = __builtin_bit_cast(u32x4, m), nu = __builtin_bit_cast(u32x4, nb), r;
  #pragma unroll
  for (int j = 0; j < 4; ++j) {
    unsigned a = (unsigned)__builtin_amdgcn_update_dpp(0, (int)mu[j], CM, 0xf, 0xf, true);
    unsigned b = (unsigned)__builtin_amdgcn_update_dpp(0, (int)nu[j], CP, 0xf, 0xf, true);
    r[j] = pl ? b : a;
  }
  return __builtin_bit_cast(short8, r);
}

#define MFMA16(A, B, C) __builtin_amdgcn_mfma_f32_16x16x32_bf16((A), (B), (C), 0, 0, 0)

// ------- fused prep: blocks 0..63 = wtrans (co), 64..575 = stats partials -------
__global__ __launch_bounds__(256) void k_prep(const float* __restrict__ x,
                                              const float* __restrict__ wk,
                                              float* __restrict__ part,
                                              u16* __restrict__ wt) {
  const int tid = threadIdx.x;
  if (blockIdx.x < 64) {
    __shared__ float lw[2592];  // [ci(32)][tap(81)]
    const int co = blockIdx.x;
    const float4* src = reinterpret_cast<const float4*>(wk + (size_t)co * 2592);
    #pragma unroll
    for (int k = 0; k < 3; ++k) {
      const int i = tid + k * 256;
      if (i < 648) ((float4*)lw)[i] = src[i];
    }
    __syncthreads();
    for (int g = tid; g < 324; g += 256) {  // tap(81) x kcg(4)
      const int tap = g >> 2, kcg = g & 3;
      u32x4 o;
      #pragma unroll
      for (int j = 0; j < 4; ++j) {
        const unsigned lo = f2bf(lw[(kcg * 8 + 2 * j + 0) * 81 + tap]);
        const unsigned hi = f2bf(lw[(kcg * 8 + 2 * j + 1) * 81 + tap]);
        o[j] = lo | (hi << 16);
      }
      *(u32x4*)(wt + (size_t)tap * 2048 + co * 32 + kcg * 8) = o;
    }
    return;
  }
  const int sbid = blockIdx.x - 64;
  const int slice = sbid >> 3;
  const int p = sbid & 7;
  const float4* base = reinterpret_cast<const float4*>(x + (size_t)slice * kSliceN);
  const int per = (kSliceN / 4) / kP;  // 3456
  const int start = p * per;
  float s = 0.f, sq = 0.f;
  for (int i = start + tid; i < start + per; i += 256) {
    float4 v = base[i];
    s += (v.x + v.y) + (v.z + v.w);
    sq += (v.x * v.x + v.y * v.y) + (v.z * v.z + v.w * v.w);
  }
  #pragma unroll
  for (int off = 32; off > 0; off >>= 1) {
    s += __shfl_down(s, off);
    sq += __shfl_down(sq, off);
  }
  __shared__ float red[2][4];
  const int wave = tid >> 6;
  if ((tid & 63) == 0) { red[0][wave] = s; red[1][wave] = sq; }
  __syncthreads();
  if (tid == 0) {
    s = (red[0][0] + red[0][1]) + (red[0][2] + red[0][3]);
    sq = (red[1][0] + red[1][1]) + (red[1][2] + red[1][3]);
    part[sbid * 2 + 0] = s;
    part[sbid * 2 + 1] = sq;
  }
}

// ---------------- norm+relu -> channels-last bf16, swizzled granule rows ----------
__global__ __launch_bounds__(256) void k_norm(const float* __restrict__ x,
                                              const float* __restrict__ part,
                                              u16* __restrict__ xn) {
  __shared__ u16 ls[6 * 1536];  // [hy][ci][w]
  __shared__ float sm[32], sr[32];
  const int tid = threadIdx.x;
  const int bid = blockIdx.x;
  const int hs = bid & 7;
  const int dz = (bid >> 3) % 48;
  const int t = bid / 384;
  const int hy0 = hs * 6;

  if (tid < 32) {
    const int slice = tid * 2 + t;
    float s = 0.f, sq = 0.f;
    #pragma unroll
    for (int p = 0; p < kP; ++p) {
      s += part[(slice * kP + p) * 2 + 0];
      sq += part[(slice * kP + p) * 2 + 1];
    }
    const float inv_n = 1.0f / (float)kSliceN;
    const float mean = s * inv_n;
    const float var = sq * inv_n - mean * mean;
    sm[tid] = mean;
    sr[tid] = rsqrtf(var + 1e-5f);
  }
  __syncthreads();

  #pragma unroll
  for (int k = 0; k < 9; ++k) {
    const int F = tid + k * 256;  // ci*72 + hy*12 + wc
    const int ci = F / 72;
    const int rem = F - ci * 72;
    const int hy = rem / 12;
    const int wc = rem - hy * 12;
    const float4 v = *reinterpret_cast<const float4*>(
        x + (size_t)(ci * 2 + t) * 110592 + dz * 2304 + (hy0 + hy) * 48 + wc * 4);
    const float mean = sm[ci], rstd = sr[ci];
    const unsigned a0 = f2bf(fmaxf((v.x - mean) * rstd, 0.f));
    const unsigned a1 = f2bf(fmaxf((v.y - mean) * rstd, 0.f));
    const unsigned a2 = f2bf(fmaxf((v.z - mean) * rstd, 0.f));
    const unsigned a3 = f2bf(fmaxf((v.w - mean) * rstd, 0.f));
    uint2 pk;
    pk.x = a0 | (a1 << 16);
    pk.y = a2 | (a3 << 16);
    *reinterpret_cast<uint2*>(ls + hy * 1536 + ci * 48 + wc * 4) = pk;
  }
  __syncthreads();

  const size_t rb = ((size_t)(t * 48 + dz) * 48 + hy0) * 1536;
  #pragma unroll
  for (int k = 0; k < 5; ++k) {
    const int g = tid + k * 256;  // hy*192 + kcg*48 + w
    if (g >= 1152) break;
    const int hy = g / 192;
    const int rem = g - hy * 192;
    const int kcg = rem / 48;
    const int w = rem - kcg * 48;
    const u16* base = ls + hy * 1536 + w;
    u32x4 o;
    #pragma unroll
    for (int j = 0; j < 4; ++j) {
      const unsigned lo = base[(kcg * 8 + 2 * j + 0) * 48];
      const unsigned hi = base[(kcg * 8 + 2 * j + 1) * 48];
      o[j] = lo | (hi << 16);
    }
    const int q = w >> 2;
    const int gd = q * 16 + ((kcg ^ (q & 3)) << 2) + (w & 3);
    *(u32x4*)(xn + rb + (size_t)hy * 1536 + gd * 8) = o;
  }
}

// ---------------- MFMA implicit-GEMM conv: 2-phase tin-pipelined staging ----------
// Block: 256 thr (4 waves) = (to, dz, 6 h-rows) x 64 co. Wave wid owns co group
// wid*16..+15, all 18 M-frags. Staging of tin_k(dd+1) is issued right after the
// barrier ending reads of tin_k(dd) and is covered by the other tin's compute.
// Grid 768 = 2 to x 8 ht x 48 dz = exactly 3 blocks/CU; bijective XCD swizzle.
__global__ __launch_bounds__(256, 3) void k_conv(const u16* __restrict__ xn,
                                                 const u16* __restrict__ wt,
                                                 const float* __restrict__ bias,
                                                 float* __restrict__ out) {
  __shared__ u16 xs[16 * 1536];  // [tin(2)][r(8)] rows (48w x 32ci swizzled), 49152 B
  const int tid = threadIdx.x, wid = tid >> 6, lane = tid & 63;
  const int r15 = lane & 15, kc = lane >> 4;

  const int orig = blockIdx.x;
  const int swz = (orig & 7) * 96 + (orig >> 3);  // bijective on [0,768)
  const int to = swz & 1;
  const int ht = (swz >> 1) & 7;
  const int dz = swz >> 4;  // 0..47
  const int h0 = ht * 6;

  {  // zero full buffer once (h-edge rows rely on staying zero; skip set dd-invariant)
    f32x4 z = {0.f, 0.f, 0.f, 0.f};
    f32x4* p = (f32x4*)xs;
    #pragma unroll
    for (int k = 0; k < 12; ++k) p[tid + k * 256] = z;
  }

  int grano[3];
  #pragma unroll
  for (int wf = 0; wf < 3; ++wf) {
    const int w = wf * 16 + r15, q = w >> 2;
    grano[wf] = (q * 16 + ((kc ^ (q & 3)) << 2) + (w & 3)) << 4;  // byte offset
  }
  const bool pl0 = (r15 == 0), pl15 = (r15 == 15);

  f32x4 acc[6][3];  // [m_row][wf]
  #pragma unroll
  for (int m = 0; m < 6; ++m)
    #pragma unroll
    for (int wf = 0; wf < 3; ++wf) acc[m][wf] = (f32x4){0.f, 0.f, 0.f, 0.f};

  // stage one tin's 8 rows (2 per wave) of slab dd
  auto STAGE = [&](int dd, int tin) {
    const int din = dz + dd - 1;
    #pragma unroll
    for (int k = 0; k < 2; ++k) {
      const int rr = wid + k * 4;  // 0..7, wave-uniform
      const int hin = h0 - 1 + rr;
      if (hin < 0 || hin >= 48) continue;  // wave-uniform skip (row stays zero)
      const u16* src = xn + ((size_t)((tin * 48 + din) * 48 + hin)) * 1536 + lane * 8;
      u16* dstb = xs + (tin * 8 + rr) * 1536;
      #pragma unroll
      for (int p = 0; p < 3; ++p) gl_lds16(src + p * 512, dstb + p * 512);
    }
  };

  // compute one (dd, tin): per-input-row hoisted DPP, m = r - kh
  auto COMPUTE = [&](int dd, int tin) {
    const int kt = tin + 1 - to;
    short8 wB[3][3];  // [kh][kw]
    #pragma unroll
    for (int kh = 0; kh < 3; ++kh)
      #pragma unroll
      for (int kw = 0; kw < 3; ++kw)
        wB[kh][kw] = *(const short8*)(wt +
            (size_t)(((kt * 3 + dd) * 3 + kh) * 3 + kw) * 2048 +
            wid * 512 + r15 * 32 + kc * 8);
    __builtin_amdgcn_s_setprio(1);
    #pragma unroll
    for (int r = 0; r < 8; ++r) {
      const char* rb = (const char*)(xs + (tin * 8 + r) * 1536);
      const short8 aC0 = *(const short8*)(rb + grano[0]);
      const short8 aC1 = *(const short8*)(rb + grano[1]);
      const short8 aC2 = *(const short8*)(rb + grano[2]);
      const short8 aL0 = dpp4<SHR1>(aC0);
      const short8 aL1 = dpp4p<SHR1, SHL15>(aC1, aC0, pl0);
      const short8 aL2 = dpp4p<SHR1, SHL15>(aC2, aC1, pl0);
      const short8 aR0 = dpp4p<SHL1, SHR15>(aC0, aC1, pl15);
      const short8 aR1 = dpp4p<SHL1, SHR15>(aC1, aC2, pl15);
      const short8 aR2 = dpp4<SHL1>(aC2);
      #pragma unroll
      for (int kh = 0; kh < 3; ++kh) {
        const int m = r - kh;
        if (m < 0 || m > 5) continue;  // compile-time
        acc[m][0] = MFMA16(wB[kh][0], aL0, acc[m][0]);
        acc[m][0] = MFMA16(wB[kh][1], aC0, acc[m][0]);
        acc[m][0] = MFMA16(wB[kh][2], aR0, acc[m][0]);
        acc[m][1] = MFMA16(wB[kh][0], aL1, acc[m][1]);
        acc[m][1] = MFMA16(wB[kh][1], aC1, acc[m][1]);
        acc[m][1] = MFMA16(wB[kh][2], aR1, acc[m][1]);
        acc[m][2] = MFMA16(wB[kh][0], aL2, acc[m][2]);
        acc[m][2] = MFMA16(wB[kh][1], aC2, acc[m][2]);
        acc[m][2] = MFMA16(wB[kh][2], aR2, acc[m][2]);
      }
    }
    __builtin_amdgcn_s_setprio(0);
  };

  __syncthreads();  // zero-init visible before first staging writes
  if (dz >= 1) { STAGE(0, 0); STAGE(0, 1); }
  __syncthreads();  // slab 0 ready (drains gl_lds)

  for (int dd = 0; dd < 3; ++dd) {
    const int din = dz + dd - 1;
    const bool vd = (din >= 0) && (din < 48);
    const bool vn = (dd < 2) && (dz + dd < 48);
    if (vd) COMPUTE(dd, 0);
    __syncthreads();           // tin0(dd) reads done; drains tin1(dd)-era loads
    if (vn) STAGE(dd + 1, 0);  // covered by tin1 compute below
    if (vd) COMPUTE(dd, 1);
    __syncthreads();           // tin1(dd) reads done; drains tin0(dd+1) stage
    if (vn) STAGE(dd + 1, 1);  // covered by tin0(dd+1) compute next iter
  }

  // epilogue: C row = co = wid*16 + kc*4 + j, col = w = wf*16 + r15
  float bv[4];
  #pragma unroll
  for (int j = 0; j < 4; ++j) bv[j] = bias[wid * 16 + kc * 4 + j];
  #pragma unroll
  for (int m = 0; m < 6; ++m) {
    const int hy = h0 + m;
    float* ob = out + (size_t)to * 110592 + (size_t)dz * 2304 + (size_t)hy * 48;
    #pragma unroll
    for (int wf = 0; wf < 3; ++wf) {
      const int w = wf * 16 + r15;
      #pragma unroll
      for (int j = 0; j < 4; ++j) {
        const int co = wid * 16 + kc * 4 + j;
        ob[(size_t)co * 221184 + w] = acc[m][wf][j] + bv[j];
      }
    }
  }
}

}  // namespace

extern "C" void kernel_launch(void* const* d_in, const int* in_sizes, int n_in,
                              void* d_out, int out_size, void* d_ws, size_t ws_size,
                              hipStream_t stream) {
  const float* x = (const float*)d_in[0];
  const float* wk = (const float*)d_in[1];
  const float* bias = (const float*)d_in[2];
  float* out = (float*)d_out;

  float* part = (float*)d_ws;            // 1024 f32 = 4096 B
  u16* xn = (u16*)((char*)d_ws + 4096);  // 2*48^3*32 u16 = 14155776 B (swizzled rows)
  u16* wt = xn + 7077888;                // 165888 u16

  k_prep<<<dim3(576), dim3(256), 0, stream>>>(x, wk, part, wt);
  k_norm<<<dim3(768), dim3(256), 0, stream>>>(x, part, xn);
  k_conv<<<dim3(768), dim3(256), 0, stream>>>(xn, wt, bias, out);
}

// Round 9
// 134.387 us; speedup vs baseline: 1.0916x; 1.0916x over previous
//
#include <hip/hip_runtime.h>

namespace {

typedef unsigned short u16;
typedef __attribute__((ext_vector_type(8))) short short8;
typedef __attribute__((ext_vector_type(4))) float f32x4;
typedef __attribute__((ext_vector_type(4))) unsigned int u32x4;

constexpr int kD = 48;
constexpr int kSliceN = kD * kD * kD;  // 110592
constexpr int kP = 8;                  // partials per (c,t) slice

__device__ inline u16 f2bf(float f) {
  unsigned u = __float_as_uint(f);
  u += 0x7fffu + ((u >> 16) & 1u);  // RNE
  return (u16)(u >> 16);
}

__device__ inline void gl_lds16(const void* g, void* l) {
  __builtin_amdgcn_global_load_lds(
      (const __attribute__((address_space(1))) unsigned int*)g,
      (__attribute__((address_space(3))) unsigned int*)l, 16, 0, 0);
}

#define MFMA16(A, B, C) __builtin_amdgcn_mfma_f32_16x16x32_bf16((A), (B), (C), 0, 0, 0)

// ------- fused prep: blocks 0..63 = wtrans (co), 64..575 = stats partials -------
__global__ __launch_bounds__(256) void k_prep(const float* __restrict__ x,
                                              const float* __restrict__ wk,
                                              float* __restrict__ part,
                                              u16* __restrict__ wt) {
  const int tid = threadIdx.x;
  if (blockIdx.x < 64) {
    __shared__ float lw[2592];  // [ci(32)][tap(81)]
    const int co = blockIdx.x;
    const float4* src = reinterpret_cast<const float4*>(wk + (size_t)co * 2592);
    #pragma unroll
    for (int k = 0; k < 3; ++k) {
      const int i = tid + k * 256;
      if (i < 648) ((float4*)lw)[i] = src[i];
    }
    __syncthreads();
    for (int g = tid; g < 324; g += 256) {  // tap(81) x kcg(4)
      const int tap = g >> 2, kcg = g & 3;
      u32x4 o;
      #pragma unroll
      for (int j = 0; j < 4; ++j) {
        const unsigned lo = f2bf(lw[(kcg * 8 + 2 * j + 0) * 81 + tap]);
        const unsigned hi = f2bf(lw[(kcg * 8 + 2 * j + 1) * 81 + tap]);
        o[j] = lo | (hi << 16);
      }
      *(u32x4*)(wt + (size_t)tap * 2048 + co * 32 + kcg * 8) = o;
    }
    return;
  }
  const int sbid = blockIdx.x - 64;
  const int slice = sbid >> 3;
  const int p = sbid & 7;
  const float4* base = reinterpret_cast<const float4*>(x + (size_t)slice * kSliceN);
  const int per = (kSliceN / 4) / kP;  // 3456
  const int start = p * per;
  float s = 0.f, sq = 0.f;
  for (int i = start + tid; i < start + per; i += 256) {
    float4 v = base[i];
    s += (v.x + v.y) + (v.z + v.w);
    sq += (v.x * v.x + v.y * v.y) + (v.z * v.z + v.w * v.w);
  }
  #pragma unroll
  for (int off = 32; off > 0; off >>= 1) {
    s += __shfl_down(s, off);
    sq += __shfl_down(sq, off);
  }
  __shared__ float red[2][4];
  const int wave = tid >> 6;
  if ((tid & 63) == 0) { red[0][wave] = s; red[1][wave] = sq; }
  __syncthreads();
  if (tid == 0) {
    s = (red[0][0] + red[0][1]) + (red[0][2] + red[0][3]);
    sq = (red[1][0] + red[1][1]) + (red[1][2] + red[1][3]);
    part[sbid * 2 + 0] = s;
    part[sbid * 2 + 1] = sq;
  }
}

// ---------------- norm+relu -> channels-last bf16, LINEAR rows ----------------
// xn row (t,dz,hy) = [w(48)][ci(32)] u16, linear. 768 blocks, 6 hy rows each.
__global__ __launch_bounds__(256) void k_norm(const float* __restrict__ x,
                                              const float* __restrict__ part,
                                              u16* __restrict__ xn) {
  __shared__ u16 ls[6 * 1536];  // [hy][ci][w] : hy*1536 + ci*48 + w
  __shared__ float sm[32], sr[32];
  const int tid = threadIdx.x;
  const int bid = blockIdx.x;
  const int hs = bid & 7;
  const int dz = (bid >> 3) % 48;
  const int t = bid / 384;
  const int hy0 = hs * 6;

  if (tid < 32) {
    const int slice = tid * 2 + t;
    float s = 0.f, sq = 0.f;
    #pragma unroll
    for (int p = 0; p < kP; ++p) {
      s += part[(slice * kP + p) * 2 + 0];
      sq += part[(slice * kP + p) * 2 + 1];
    }
    const float inv_n = 1.0f / (float)kSliceN;
    const float mean = s * inv_n;
    const float var = sq * inv_n - mean * mean;
    sm[tid] = mean;
    sr[tid] = rsqrtf(var + 1e-5f);
  }
  __syncthreads();

  // stage 1: 2304 float4 coalesced loads, normalize+relu, bf16 -> LDS
  #pragma unroll
  for (int k = 0; k < 9; ++k) {
    const int F = tid + k * 256;  // ci*72 + hy*12 + wc
    const int ci = F / 72;
    const int rem = F - ci * 72;
    const int hy = rem / 12;
    const int wc = rem - hy * 12;
    const float4 v = *reinterpret_cast<const float4*>(
        x + (size_t)(ci * 2 + t) * 110592 + dz * 2304 + (hy0 + hy) * 48 + wc * 4);
    const float mean = sm[ci], rstd = sr[ci];
    const unsigned a0 = f2bf(fmaxf((v.x - mean) * rstd, 0.f));
    const unsigned a1 = f2bf(fmaxf((v.y - mean) * rstd, 0.f));
    const unsigned a2 = f2bf(fmaxf((v.z - mean) * rstd, 0.f));
    const unsigned a3 = f2bf(fmaxf((v.w - mean) * rstd, 0.f));
    uint2 pk;
    pk.x = a0 | (a1 << 16);
    pk.y = a2 | (a3 << 16);
    *reinterpret_cast<uint2*>(ls + hy * 1536 + ci * 48 + wc * 4) = pk;
  }
  __syncthreads();

  // stage 2: gather 8 ci per (hy,w,kcg), pack, store linear [w][ci] (coalesced)
  const size_t rb = ((size_t)(t * 48 + dz) * 48 + hy0) * 1536;
  #pragma unroll
  for (int k = 0; k < 5; ++k) {
    const int g = tid + k * 256;  // hy*192 + w*4 + kcg
    if (g >= 1152) break;
    const int hy = g / 192;
    const int rem = g - hy * 192;
    const int w = rem >> 2;
    const int kcg = rem & 3;
    const u16* base = ls + hy * 1536 + w;
    u32x4 o;
    #pragma unroll
    for (int j = 0; j < 4; ++j) {
      const unsigned lo = base[(kcg * 8 + 2 * j + 0) * 48];
      const unsigned hi = base[(kcg * 8 + 2 * j + 1) * 48];
      o[j] = lo | (hi << 16);
    }
    *(u32x4*)(xn + rb + (size_t)hy * 1536 + w * 32 + kcg * 8) = o;
  }
}

// ---------------- MFMA implicit-GEMM conv: halo-LDS shifted reads ----------
// Block: 256 thr (4 waves) = (to, dz, 6 h-rows) x 64 co. Wave wid owns co group
// wid*16..+15, all 18 M-frags. LDS rows are [50 w][32 ci] with zero halo at
// w-slots 0 and 49; kw-shifted A-frags are direct ds_read_b128 at +-64 B.
// Grid 768 = 2 to x 8 ht x 48 dz = exactly 3 blocks/CU; bijective XCD swizzle.
__global__ __launch_bounds__(256, 3) void k_conv(const u16* __restrict__ xn,
                                                 const u16* __restrict__ wt,
                                                 const float* __restrict__ bias,
                                                 float* __restrict__ out) {
  __shared__ u16 xs[16 * 1600];  // [tin(2)][r(8)] rows of [50][32], 51200 B
  const int tid = threadIdx.x, wid = tid >> 6, lane = tid & 63;
  const int r15 = lane & 15, kc = lane >> 4;

  const int orig = blockIdx.x;
  const int swz = (orig & 7) * 96 + (orig >> 3);  // bijective on [0,768)
  const int to = swz & 1;
  const int ht = (swz >> 1) & 7;
  const int dz = swz >> 4;  // 0..47
  const int h0 = ht * 6;

  {  // zero full buffer once (halo slots + h-edge rows rely on staying zero)
    f32x4 z = {0.f, 0.f, 0.f, 0.f};
    f32x4* p = (f32x4*)xs;
    #pragma unroll
    for (int k = 0; k < 13; ++k) {
      const int i = tid + k * 256;
      if (i < 3200) p[i] = z;
    }
  }

  const int coff = r15 * 64 + kc * 16;  // byte offset within a w-frag read

  f32x4 acc[6][3];  // [m_row][wf]
  #pragma unroll
  for (int m = 0; m < 6; ++m)
    #pragma unroll
    for (int wf = 0; wf < 3; ++wf) acc[m][wf] = (f32x4){0.f, 0.f, 0.f, 0.f};

  __syncthreads();  // zero-init visible before first staging writes

  for (int dd = 0; dd < 3; ++dd) {
    const int din = dz + dd - 1;
    const bool vd = (din >= 0) && (din < 48);
    if (vd) {
      for (int u = wid; u < 16; u += 4) {  // 4 rows per wave, wave-uniform
        const int tin = u >> 3, rr = u & 7;
        const int hin = h0 - 1 + rr;
        if (hin < 0 || hin >= 48) continue;  // wave-uniform skip (row stays zero)
        const u16* src = xn + ((size_t)((tin * 48 + din) * 48 + hin)) * 1536 + lane * 8;
        u16* dstb = xs + u * 1600 + 32;  // payload starts at w-slot 1
        #pragma unroll
        for (int p = 0; p < 3; ++p) gl_lds16(src + p * 512, dstb + p * 512);
      }
    }
    __syncthreads();  // staged data visible (drains gl_lds)
    if (vd) {
      #pragma unroll
      for (int tin = 0; tin < 2; ++tin) {
        const int kt = tin + 1 - to;
        short8 wB[3][3];  // [kh][kw]
        #pragma unroll
        for (int kh = 0; kh < 3; ++kh)
          #pragma unroll
          for (int kw = 0; kw < 3; ++kw)
            wB[kh][kw] = *(const short8*)(wt +
                (size_t)(((kt * 3 + dd) * 3 + kh) * 3 + kw) * 2048 +
                wid * 512 + r15 * 32 + kc * 8);
        #pragma unroll
        for (int r = 0; r < 8; ++r) {  // input rows; m = r - kh
          const char* rb = (const char*)xs + (tin * 8 + r) * 3200;
          #pragma unroll
          for (int wf = 0; wf < 3; ++wf) {
            // dl=0 -> input w-1 (kw=0), dl=1 -> w (kw=1), dl=2 -> w+1 (kw=2)
            const short8 A0 = *(const short8*)(rb + wf * 1024 + 0 * 64 + coff);
            const short8 A1 = *(const short8*)(rb + wf * 1024 + 1 * 64 + coff);
            const short8 A2 = *(const short8*)(rb + wf * 1024 + 2 * 64 + coff);
            #pragma unroll
            for (int kh = 0; kh < 3; ++kh) {
              const int m = r - kh;
              if (m < 0 || m > 5) continue;  // compile-time
              acc[m][wf] = MFMA16(wB[kh][0], A0, acc[m][wf]);
              acc[m][wf] = MFMA16(wB[kh][1], A1, acc[m][wf]);
              acc[m][wf] = MFMA16(wB[kh][2], A2, acc[m][wf]);
            }
          }
        }
      }
    }
    __syncthreads();  // compute done before next slab overwrites xs
  }

  // epilogue: C row = co = wid*16 + kc*4 + j, col = w = wf*16 + r15
  float bv[4];
  #pragma unroll
  for (int j = 0; j < 4; ++j) bv[j] = bias[wid * 16 + kc * 4 + j];
  #pragma unroll
  for (int m = 0; m < 6; ++m) {
    const int hy = h0 + m;
    float* ob = out + (size_t)to * 110592 + (size_t)dz * 2304 + (size_t)hy * 48;
    #pragma unroll
    for (int wf = 0; wf < 3; ++wf) {
      const int w = wf * 16 + r15;
      #pragma unroll
      for (int j = 0; j < 4; ++j) {
        const int co = wid * 16 + kc * 4 + j;
        ob[(size_t)co * 221184 + w] = acc[m][wf][j] + bv[j];
      }
    }
  }
}

}  // namespace

extern "C" void kernel_launch(void* const* d_in, const int* in_sizes, int n_in,
                              void* d_out, int out_size, void* d_ws, size_t ws_size,
                              hipStream_t stream) {
  const float* x = (const float*)d_in[0];
  const float* wk = (const float*)d_in[1];
  const float* bias = (const float*)d_in[2];
  float* out = (float*)d_out;

  float* part = (float*)d_ws;            // 1024 f32 = 4096 B
  u16* xn = (u16*)((char*)d_ws + 4096);  // 2*48^3*32 u16 = 14155776 B (linear rows)
  u16* wt = xn + 7077888;                // 165888 u16

  k_prep<<<dim3(576), dim3(256), 0, stream>>>(x, wk, part, wt);
  k_norm<<<dim3(768), dim3(256), 0, stream>>>(x, part, xn);
  k_conv<<<dim3(768), dim3(256), 0, stream>>>(xn, wt, bias, out);
}